// Round 5
// baseline (456.368 us; speedup 1.0000x reference)
//
#include <hip/hip_runtime.h>
#include <hip/hip_bf16.h>

#define HID   512
#define BATCH 64
#define SRC   2048
#define MROWS (BATCH * SRC)

typedef __bf16 bf16x8 __attribute__((ext_vector_type(8)));
typedef __bf16 bf16x4 __attribute__((ext_vector_type(4)));
typedef float  f32x16 __attribute__((ext_vector_type(16)));
typedef float  f32x4n __attribute__((ext_vector_type(4)));

#define PANEL 520          // elems per A panel (512 + 8 skew) = 1040 B

__device__ inline float fast_tanh(float x) {
    float e = __builtin_amdgcn_exp2f(x * 2.8853900817779268f);
    return 1.0f - 2.0f * __builtin_amdgcn_rcpf(e + 1.0f);
}

template <int CTRL>
__device__ inline float dpp_add(float x) {
    int y = __builtin_amdgcn_update_dpp(0, __builtin_bit_cast(int, x), CTRL, 0xF, 0xF, true);
    return x + __builtin_bit_cast(float, y);
}

// sum over the 32 lanes of each 32-lane half
__device__ inline float reduce32(float x) {
    x = dpp_add<0xB1>(x);    // quad_perm xor1
    x = dpp_add<0x4E>(x);    // quad_perm xor2
    x = dpp_add<0x141>(x);   // row_half_mirror
    x = dpp_add<0x140>(x);   // row_mirror
    int y = __builtin_amdgcn_ds_swizzle(__builtin_bit_cast(int, x), 0x401F); // xor 16
    return x + __builtin_bit_cast(float, y);
}

// ---- kernel 1 (fused prep): blocks 0-127 pack W1 -> bf16 fragment order;
//      blocks 128-191: bias_comb[b,o] = h[b]·W2[o,:] + W2_b[o] + W1_b[o]
__global__ void prep(const float* __restrict__ W1w, __bf16* __restrict__ Bpk,
                     const float* __restrict__ h, const float* __restrict__ W2w,
                     const float* __restrict__ W2b, const float* __restrict__ W1b,
                     float* __restrict__ biasc) {
    __shared__ float hh[HID];
    int tid = threadIdx.x;
    if (blockIdx.x < 128) {
        // Bpk[(kt*16 + ot)*64 + lane][8]: lane l holds o=ot*32+(l&31), k=kt*16+(l>>5)*8+j
        int t = blockIdx.x * 256 + tid;
        int l = t & 63, tile = t >> 6;
        int ot = tile & 15, kt = tile >> 4;
        int o = ot * 32 + (l & 31);
        int k = kt * 16 + (l >> 5) * 8;
        const float* src = W1w + (size_t)o * HID + k;
        float4 v0 = *(const float4*)src;
        float4 v1 = *(const float4*)(src + 4);
        bf16x8 r;
        r[0]=(__bf16)v0.x; r[1]=(__bf16)v0.y; r[2]=(__bf16)v0.z; r[3]=(__bf16)v0.w;
        r[4]=(__bf16)v1.x; r[5]=(__bf16)v1.y; r[6]=(__bf16)v1.z; r[7]=(__bf16)v1.w;
        ((bf16x8*)Bpk)[t] = r;
    } else {
        int b = blockIdx.x - 128;
        hh[tid]       = h[b * HID + tid];
        hh[tid + 256] = h[b * HID + tid + 256];
        __syncthreads();
        const float4* h4 = (const float4*)hh;
        for (int o = tid; o < HID; o += 256) {
            const float4* w4 = (const float4*)(W2w + (size_t)o * HID);
            float s = 0.f;
            #pragma unroll 8
            for (int k = 0; k < HID / 4; ++k) {
                float4 a = h4[k]; float4 w = w4[k];
                s += a.x * w.x + a.y * w.y + a.z * w.z + a.w * w.w;
            }
            biasc[b * HID + o] = s + W2b[o] + W1b[o];
        }
    }
}

// ---- kernel 2: fused GEMM + tanh + V-dot. 128-row blocks, inverted loop. ----
// grid 1024 x 512 thr, 1 block/CU (137 KB LDS). Wave wv: otiles {2wv,2wv+1},
// ALL four 32-row m-tiles (8 MFMA/iter, 128 acc VGPRs). B slab read once per
// 128 rows => total B L2 traffic 0.5 GB. Depth-2 B prefetch.
__global__ __launch_bounds__(512, 2) void attn_main(
        const float* __restrict__ enc, const __bf16* __restrict__ Bpk,
        const float* __restrict__ biasc, const float* __restrict__ Vw,
        float* __restrict__ scores) {
    __shared__ __bf16 AL[128 * PANEL];    // 128 panels x 1040 B = 133120 B
    __shared__ float sred[128][9];        // + 4608 B = 137728 B total

    const int tid = threadIdx.x;
    const int blockRow = blockIdx.x * 128;
    const int b = blockIdx.x >> 4;        // 16 blocks per batch row
    const int lane = tid & 63;
    const int wv = tid >> 6;
    const int col = lane & 31;
    const int hfi = lane >> 5;

    // epilogue constants (issue early, independent)
    const int o0 = (2 * wv) * 32 + col;
    const int o1 = o0 + 32;
    float bb0 = biasc[b * HID + o0], bb1 = biasc[b * HID + o1];
    float vv0 = Vw[o0],               vv1 = Vw[o1];

    const int rot = (blockIdx.x + (blockIdx.x >> 3)) & 31;  // all-distinct per XCD
    const char* BpkB = (const char*)Bpk + (2 * wv) * 1024 + lane * 16;

    // B prefetch for first two kt (independent of LDS staging -> hides behind it)
    bf16x8 bpre[2][2];
    bpre[0][0] = *(const bf16x8*)(BpkB + (size_t)rot * 16384);
    bpre[0][1] = *(const bf16x8*)(BpkB + (size_t)rot * 16384 + 1024);
    int r1 = (rot + 1) & 31;
    bpre[1][0] = *(const bf16x8*)(BpkB + (size_t)r1 * 16384);
    bpre[1][1] = *(const bf16x8*)(BpkB + (size_t)r1 * 16384 + 1024);

    // ---- stage A: 128 rows x 512 k fp32 -> bf16 fragment order in LDS ----
    // enc read exactly once globally: non-temporal, keep L1 for B.
    const f32x4n* encB = (const f32x4n*)enc + (size_t)blockRow * 128;
    #pragma unroll 8
    for (int i = 0; i < 32; ++i) {
        int f = i * 512 + tid;            // coalesced 1KB/wave
        f32x4n v = __builtin_nontemporal_load(encB + f);
        int row = f >> 7;
        int kq  = (f & 127) << 2;
        int kt = kq >> 4, half = (kq >> 3) & 1, j = kq & 7;
        int off = (kt * 4 + (row >> 5)) * PANEL + ((row & 31) + 32 * half) * 8 + j;
        bf16x4 o4;
        o4[0]=(__bf16)v.x; o4[1]=(__bf16)v.y; o4[2]=(__bf16)v.z; o4[3]=(__bf16)v.w;
        *(bf16x4*)&AL[off] = o4;
    }

    f32x16 acc[4][2];
    #pragma unroll
    for (int mt = 0; mt < 4; ++mt)
        #pragma unroll
        for (int i = 0; i < 16; ++i) { acc[mt][0][i] = 0.f; acc[mt][1][i] = 0.f; }

    __syncthreads();                      // only barrier before epilogue

    // ---- K-loop: 32 kt steps, 8 MFMA each, depth-2 B prefetch, no barriers ----
    #pragma unroll 2
    for (int kt = 0; kt < 32; ++kt) {
        const int cur = kt & 1;
        bf16x8 ub0 = bpre[cur][0];
        bf16x8 ub1 = bpre[cur][1];
        int nk = (kt + 2 + rot) & 31;     // wraps at tail: redundant but valid
        bpre[cur][0] = *(const bf16x8*)(BpkB + (size_t)nk * 16384);
        bpre[cur][1] = *(const bf16x8*)(BpkB + (size_t)nk * 16384 + 1024);

        int ia = (kt + rot) & 31;
        const __bf16* pa = AL + ia * (4 * PANEL) + lane * 8;
        bf16x8 a0 = *(const bf16x8*)pa;
        bf16x8 a1 = *(const bf16x8*)(pa + PANEL);
        bf16x8 a2 = *(const bf16x8*)(pa + 2 * PANEL);
        bf16x8 a3 = *(const bf16x8*)(pa + 3 * PANEL);

        acc[0][0] = __builtin_amdgcn_mfma_f32_32x32x16_bf16(a0, ub0, acc[0][0], 0, 0, 0);
        acc[1][0] = __builtin_amdgcn_mfma_f32_32x32x16_bf16(a1, ub0, acc[1][0], 0, 0, 0);
        acc[2][0] = __builtin_amdgcn_mfma_f32_32x32x16_bf16(a2, ub0, acc[2][0], 0, 0, 0);
        acc[3][0] = __builtin_amdgcn_mfma_f32_32x32x16_bf16(a3, ub0, acc[3][0], 0, 0, 0);
        acc[0][1] = __builtin_amdgcn_mfma_f32_32x32x16_bf16(a0, ub1, acc[0][1], 0, 0, 0);
        acc[1][1] = __builtin_amdgcn_mfma_f32_32x32x16_bf16(a1, ub1, acc[1][1], 0, 0, 0);
        acc[2][1] = __builtin_amdgcn_mfma_f32_32x32x16_bf16(a2, ub1, acc[2][1], 0, 0, 0);
        acc[3][1] = __builtin_amdgcn_mfma_f32_32x32x16_bf16(a3, ub1, acc[3][1], 0, 0, 0);
    }

    // ---- epilogue: tanh + V-dot; DPP 32-lane reduction; cross-wave via LDS ----
    // C layout: col = lane&31, row = (r&3) + 8*(r>>2) + 4*(lane>>5)
    #pragma unroll
    for (int mt = 0; mt < 4; ++mt) {
        #pragma unroll
        for (int r = 0; r < 16; ++r) {
            float p = vv0 * fast_tanh(acc[mt][0][r] + bb0)
                    + vv1 * fast_tanh(acc[mt][1][r] + bb1);
            p = reduce32(p);
            if (col == 0) {
                int rl = mt * 32 + (r & 3) + 8 * (r >> 2) + 4 * hfi;
                sred[rl][wv] = p;
            }
        }
    }
    __syncthreads();
    if (tid < 128) {
        float s = 0.f;
        #pragma unroll
        for (int w = 0; w < 8; ++w) s += sred[tid][w];
        scores[blockRow + tid] = s;       // V_b omitted: cancels in softmax
    }
}

// ---- kernel 3: in-place softmax over S=2048 per batch row ----
__global__ void softmax_k(float* __restrict__ scores) {
    int b = blockIdx.x;
    int tid = threadIdx.x;
    int lane = tid & 63, wv = tid >> 6;
    __shared__ float red[4];
    float* row = scores + (size_t)b * SRC;
    float4 v0 = *(float4*)(row + tid * 8);
    float4 v1 = *(float4*)(row + tid * 8 + 4);
    float x[8] = {v0.x, v0.y, v0.z, v0.w, v1.x, v1.y, v1.z, v1.w};
    float mx = x[0];
    #pragma unroll
    for (int r = 1; r < 8; ++r) mx = fmaxf(mx, x[r]);
    #pragma unroll
    for (int m = 1; m <= 32; m <<= 1) mx = fmaxf(mx, __shfl_xor(mx, m, 64));
    if (lane == 0) red[wv] = mx;
    __syncthreads();
    mx = fmaxf(fmaxf(red[0], red[1]), fmaxf(red[2], red[3]));
    __syncthreads();
    float s = 0.f;
    #pragma unroll
    for (int r = 0; r < 8; ++r) {
        x[r] = __builtin_amdgcn_exp2f((x[r] - mx) * 1.44269504088896f);
        s += x[r];
    }
    #pragma unroll
    for (int m = 1; m <= 32; m <<= 1) s += __shfl_xor(s, m, 64);
    if (lane == 0) red[wv] = s;
    __syncthreads();
    s = red[0] + red[1] + red[2] + red[3];
    float inv = 1.0f / s;
    float4 o0 = make_float4(x[0] * inv, x[1] * inv, x[2] * inv, x[3] * inv);
    float4 o1 = make_float4(x[4] * inv, x[5] * inv, x[6] * inv, x[7] * inv);
    *(float4*)(row + tid * 8)     = o0;
    *(float4*)(row + tid * 8 + 4) = o1;
}

extern "C" void kernel_launch(void* const* d_in, const int* in_sizes, int n_in,
                              void* d_out, int out_size, void* d_ws, size_t ws_size,
                              hipStream_t stream) {
    const float* h    = (const float*)d_in[0];
    const float* enc  = (const float*)d_in[1];
    const float* W1w  = (const float*)d_in[2];
    const float* W1b  = (const float*)d_in[3];
    const float* W2w  = (const float*)d_in[4];
    const float* W2b  = (const float*)d_in[5];
    const float* Vw   = (const float*)d_in[6];
    // d_in[7] = V_b: constant shift cancels in softmax.
    float* out = (float*)d_out;

    __bf16* Bpk  = (__bf16*)d_ws;                                       // 512 KB
    float*  biasc = (float*)((char*)d_ws + HID * HID * sizeof(__bf16)); // 128 KB

    prep     <<<192, 256, 0, stream>>>(W1w, Bpk, h, W2w, W2b, W1b, biasc);
    attn_main<<<MROWS / 128, 512, 0, stream>>>(enc, Bpk, biasc, Vw, out);
    softmax_k<<<BATCH, 256, 0, stream>>>(out);
}